// Round 4
// baseline (618.424 us; speedup 1.0000x reference)
//
#include <hip/hip_runtime.h>

#define N_NODESC 50000
#define N_EDGESC 800000
#define N_GRAPHSC 512
#define DF 128
#define BN_EPSF 1e-5f

typedef _Float16 half8 __attribute__((ext_vector_type(8)));
typedef _Float16 half4v __attribute__((ext_vector_type(4)));
typedef _Float16 half2v __attribute__((ext_vector_type(2)));
typedef float floatx4 __attribute__((ext_vector_type(4)));

// ---------------- CSR build ----------------
__global__ __launch_bounds__(256) void k_count(const int* __restrict__ dst, int* __restrict__ counts) {
    int e = blockIdx.x * 256 + threadIdx.x;
    if (e < N_EDGESC) atomicAdd(&counts[dst[e]], 1);
}

__global__ __launch_bounds__(1024) void k_scan1(int* __restrict__ off, int* __restrict__ partials) {
    __shared__ int sh[1024];
    int t = threadIdx.x;
    int i = blockIdx.x * 1024 + t;
    int v = (i < N_NODESC) ? off[i] : 0;
    sh[t] = v;
    __syncthreads();
    for (int ofs = 1; ofs < 1024; ofs <<= 1) {
        int u = (t >= ofs) ? sh[t - ofs] : 0;
        __syncthreads();
        sh[t] += u;
        __syncthreads();
    }
    if (i < N_NODESC) off[i] = sh[t] - v;  // local exclusive
    if (t == 1023) partials[blockIdx.x] = sh[1023];
}

__global__ __launch_bounds__(64) void k_scan2(int* __restrict__ partials, int nparts) {
    __shared__ int sh[64];
    int t = threadIdx.x;
    sh[t] = (t < nparts) ? partials[t] : 0;
    __syncthreads();
    for (int ofs = 1; ofs < 64; ofs <<= 1) {
        int u = (t >= ofs) ? sh[t - ofs] : 0;
        __syncthreads();
        sh[t] += u;
        __syncthreads();
    }
    if (t < nparts) partials[t] = sh[t];
}

__global__ __launch_bounds__(1024) void k_scan3(int* __restrict__ off, const int* __restrict__ partials,
                                                int* __restrict__ cursor) {
    int t = threadIdx.x;
    int i = blockIdx.x * 1024 + t;
    if (i < N_NODESC) {
        int base = blockIdx.x ? partials[blockIdx.x - 1] : 0;
        int o = off[i] + base;
        off[i] = o;
        cursor[i] = o;
    }
    if (i == 0) off[N_NODESC] = N_EDGESC;
}

__global__ __launch_bounds__(256) void k_scatter(const int* __restrict__ src, const int* __restrict__ dst,
                                                 int* __restrict__ cursor, int* __restrict__ csr) {
    int e = blockIdx.x * 256 + threadIdx.x;
    if (e < N_EDGESC) {
        int d = dst[e];
        int pos = atomicAdd(&cursor[d], 1);
        csr[pos] = src[e];
    }
}

// ---------------- x fp32 -> fp16 ----------------
__global__ __launch_bounds__(256) void k_convX(const float* __restrict__ x, _Float16* __restrict__ h) {
    int i4 = blockIdx.x * 256 + threadIdx.x;
    if (i4 >= N_NODESC * DF / 4) return;
    float4 v = ((const float4*)x)[i4];
    half4v o;
    o[0] = (_Float16)v.x; o[1] = (_Float16)v.y; o[2] = (_Float16)v.z; o[3] = (_Float16)v.w;
    ((half4v*)h)[i4] = o;
}

// ---------------- weight repack: fp32 [k][n] -> fp16 B-fragment order ----------------
__global__ __launch_bounds__(256) void k_convW(const float* __restrict__ W1, const float* __restrict__ W2,
                                               half8* __restrict__ wf) {
    int t = blockIdx.x * 256 + threadIdx.x;
    if (t >= 6 * 2048) return;
    int m = t >> 11;
    int p = t & 2047;
    int ntile = p >> 8;
    int ks = (p >> 6) & 3;
    int l = p & 63;
    int n = ntile * 16 + (l & 15);
    int kb = ks * 32 + (l >> 4) * 8;
    const float* W = (m < 3) ? (W1 + (size_t)m * DF * DF) : (W2 + (size_t)(m - 3) * DF * DF);
    half8 o;
#pragma unroll
    for (int j = 0; j < 8; j++) o[j] = (_Float16)W[(size_t)(kb + j) * DF + n];
    wf[t] = o;
}

// ---------------- fused layer: gather(+BN-affine+relu of prev) -> MLP1 -> MLP2 -> stats -> z ----------------
// MODE 0: first layer, Hin = fp16 x (identity input transform)
// MODE 1: mid layer,  Hin = z_prev fp16; input transform = relu(z*sc + of) from st_prev/gamma/beta
// Block = 256 threads = 4 waves; wave w owns rows [blk*64 + w*16, +16) end-to-end.
// LDS tile rows are touched only intra-wave (in-order DS pipe) -> no __syncthreads needed.
#define TSTRIDE 136  // 128 + 8 halfs pad
template <int MODE>
__global__ __launch_bounds__(256) void k_fused(
    const _Float16* __restrict__ Hin,
    const int* __restrict__ off, const int* __restrict__ csr,
    const float* __restrict__ epsArr, int layer,
    const float* __restrict__ st_prev, const float* __restrict__ gprev, const float* __restrict__ bprev,
    const half8* __restrict__ W1f, const float* __restrict__ b1,
    const half8* __restrict__ W2f, const float* __restrict__ b2,
    _Float16* __restrict__ Z, float* __restrict__ st_out)
{
    __shared__ _Float16 tile[64 * TSTRIDE];  // 17 KB
    const int tid = threadIdx.x;
    const int wave = tid >> 6, lane = tid & 63;
    const int q = lane >> 4, c = lane & 15;

    // input-transform coefficients for this lane's 2 columns (2*lane, 2*lane+1)
    float sc0 = 1.f, of0 = 0.f, sc1 = 1.f, of1 = 0.f;
    if (MODE == 1) {
        const float invN = 1.f / (float)N_NODESC;
        int c0 = 2 * lane, c1 = c0 + 1;
        float m0 = st_prev[c0] * invN;
        float v0 = st_prev[DF + c0] * invN - m0 * m0;
        sc0 = gprev[c0] * rsqrtf(v0 + BN_EPSF);
        of0 = bprev[c0] - m0 * sc0;
        float m1 = st_prev[c1] * invN;
        float v1 = st_prev[DF + c1] * invN - m1 * m1;
        sc1 = gprev[c1] * rsqrtf(v1 + BN_EPSF);
        of1 = bprev[c1] - m1 * sc1;
    }
    const float e1 = 1.f + epsArr[layer];
    const half2v* Hr = (const half2v*)Hin;

    // ---- phase 1: gather 16 nodes into this wave's tile rows ----
    int nbase = blockIdx.x * 64 + wave * 16;
#pragma unroll 1
    for (int i = 0; i < 16; i++) {
        int n = nbase + i;
        float a0 = 0.f, a1 = 0.f;
        if (n < N_NODESC) {
            half2v v = Hr[(size_t)n * 64 + lane];
            float h0, h1;
            if (MODE == 1) {
                h0 = fmaxf((float)v[0] * sc0 + of0, 0.f);
                h1 = fmaxf((float)v[1] * sc1 + of1, 0.f);
            } else {
                h0 = (float)v[0];
                h1 = (float)v[1];
            }
            a0 = e1 * h0;
            a1 = e1 * h1;
            int s = off[n], t = off[n + 1];
            int k = s;
            for (; k + 4 <= t; k += 4) {
                int m0_ = csr[k], m1_ = csr[k + 1], m2_ = csr[k + 2], m3_ = csr[k + 3];
                half2v u0 = Hr[(size_t)m0_ * 64 + lane];
                half2v u1 = Hr[(size_t)m1_ * 64 + lane];
                half2v u2 = Hr[(size_t)m2_ * 64 + lane];
                half2v u3 = Hr[(size_t)m3_ * 64 + lane];
                if (MODE == 1) {
                    a0 += fmaxf((float)u0[0] * sc0 + of0, 0.f) + fmaxf((float)u1[0] * sc0 + of0, 0.f)
                        + fmaxf((float)u2[0] * sc0 + of0, 0.f) + fmaxf((float)u3[0] * sc0 + of0, 0.f);
                    a1 += fmaxf((float)u0[1] * sc1 + of1, 0.f) + fmaxf((float)u1[1] * sc1 + of1, 0.f)
                        + fmaxf((float)u2[1] * sc1 + of1, 0.f) + fmaxf((float)u3[1] * sc1 + of1, 0.f);
                } else {
                    a0 += (float)u0[0] + (float)u1[0] + (float)u2[0] + (float)u3[0];
                    a1 += (float)u0[1] + (float)u1[1] + (float)u2[1] + (float)u3[1];
                }
            }
            for (; k < t; k++) {
                half2v u = Hr[(size_t)csr[k] * 64 + lane];
                if (MODE == 1) {
                    a0 += fmaxf((float)u[0] * sc0 + of0, 0.f);
                    a1 += fmaxf((float)u[1] * sc1 + of1, 0.f);
                } else {
                    a0 += (float)u[0];
                    a1 += (float)u[1];
                }
            }
        }
        half2v o;
        o[0] = (_Float16)a0;
        o[1] = (_Float16)a1;
        *(half2v*)&tile[(wave * 16 + i) * TSTRIDE + 2 * lane] = o;
    }

    // ---- phase 2: gemm1 (A from LDS, W1 frags from global/L2) ----
    const int myrow = wave * 16 + c;
    half8 af[4];
#pragma unroll
    for (int ks = 0; ks < 4; ks++)
        af[ks] = *(const half8*)&tile[myrow * TSTRIDE + ks * 32 + q * 8];

    floatx4 acc[8];
#pragma unroll
    for (int nt = 0; nt < 8; nt++) acc[nt] = (floatx4)(0.0f);
#pragma unroll
    for (int ks = 0; ks < 4; ks++) {
#pragma unroll
        for (int nt = 0; nt < 8; nt++) {
            half8 wfr = W1f[(nt * 4 + ks) * 64 + lane];
            acc[nt] = __builtin_amdgcn_mfma_f32_16x16x32_f16(af[ks], wfr, acc[nt], 0, 0, 0);
        }
    }

    // epilogue 1: bias + relu -> fp16 -> tile (B), rows wave*16 + q*4 + r (intra-wave overwrite of A rows)
    const int rbase = wave * 16 + q * 4;
#pragma unroll
    for (int nt = 0; nt < 8; nt++) {
        float b = b1[nt * 16 + c];
#pragma unroll
        for (int r = 0; r < 4; r++) {
            float vv = fmaxf(acc[nt][r] + b, 0.f);
            tile[(rbase + r) * TSTRIDE + nt * 16 + c] = (_Float16)vv;
        }
    }

    // ---- phase 3: gemm2 ----
    half8 bf[4];
#pragma unroll
    for (int ks = 0; ks < 4; ks++)
        bf[ks] = *(const half8*)&tile[myrow * TSTRIDE + ks * 32 + q * 8];

    floatx4 acc2[8];
#pragma unroll
    for (int nt = 0; nt < 8; nt++) acc2[nt] = (floatx4)(0.0f);
#pragma unroll
    for (int ks = 0; ks < 4; ks++) {
#pragma unroll
        for (int nt = 0; nt < 8; nt++) {
            half8 wfr = W2f[(nt * 4 + ks) * 64 + lane];
            acc2[nt] = __builtin_amdgcn_mfma_f32_16x16x32_f16(bf[ks], wfr, acc2[nt], 0, 0, 0);
        }
    }

    // epilogue 2: bias, per-column stats (fp32, pre-rounding), z-tile -> coalesced global store
    float s1[8], s2[8];
    const int growbase = blockIdx.x * 64 + rbase;
#pragma unroll
    for (int nt = 0; nt < 8; nt++) {
        float b = b2[nt * 16 + c];
        float ls = 0.f, lq = 0.f;
#pragma unroll
        for (int r = 0; r < 4; r++) {
            float vv = acc2[nt][r] + b;
            if (growbase + r < N_NODESC) {
                ls += vv;
                lq += vv * vv;
            }
            tile[(rbase + r) * TSTRIDE + nt * 16 + c] = (_Float16)vv;
        }
        s1[nt] = ls;
        s2[nt] = lq;
    }

    // coalesced z store: 4 iterations x (4 rows x 256 B) per wave
#pragma unroll
    for (int i = 0; i < 4; i++) {
        int lr = wave * 16 + i * 4 + (lane >> 4);
        int grow = blockIdx.x * 64 + lr;
        half8 vz = *(const half8*)&tile[lr * TSTRIDE + (lane & 15) * 8];
        if (grow < N_NODESC)
            *(half8*)&Z[(size_t)grow * DF + (lane & 15) * 8] = vz;
    }

    // stats: reduce over the 4 q-groups, then q==0 lanes push one atomic per (col, kind)
#pragma unroll
    for (int nt = 0; nt < 8; nt++) {
        s1[nt] += __shfl_xor(s1[nt], 16);
        s1[nt] += __shfl_xor(s1[nt], 32);
        s2[nt] += __shfl_xor(s2[nt], 16);
        s2[nt] += __shfl_xor(s2[nt], 32);
    }
    if (q == 0) {
#pragma unroll
        for (int nt = 0; nt < 8; nt++) {
            atomicAdd(&st_out[nt * 16 + c], s1[nt]);
            atomicAdd(&st_out[DF + nt * 16 + c], s2[nt]);
        }
    }
}

// ---------------- global mean pool with folded BN affine (last layer, no relu) ----------------
static __device__ int lbound(const int* __restrict__ a, int n, int key) {
    int lo = 0, hi = n;
    while (lo < hi) {
        int mid = (lo + hi) >> 1;
        if (a[mid] < key) lo = mid + 1; else hi = mid;
    }
    return lo;
}

__global__ __launch_bounds__(128) void k_pool(const _Float16* __restrict__ Z, const int* __restrict__ batch,
                                              const float* __restrict__ st, const float* __restrict__ gamma,
                                              const float* __restrict__ beta, float* __restrict__ out) {
    __shared__ int bnds[2];
    int g = blockIdx.x, c = threadIdx.x;
    if (threadIdx.x == 0) {
        bnds[0] = lbound(batch, N_NODESC, g);
        bnds[1] = lbound(batch, N_NODESC, g + 1);
    }
    __syncthreads();
    const float invN = 1.f / (float)N_NODESC;
    float m = st[c] * invN;
    float v = st[DF + c] * invN - m * m;
    float sc = gamma[c] * rsqrtf(v + BN_EPSF);
    float of = beta[c] - m * sc;
    int lo = bnds[0], hi = bnds[1];
    float s = 0.f;
    for (int r = lo; r < hi; r++) s += (float)Z[(size_t)r * DF + c];
    int cnt = hi - lo;
    out[g * DF + c] = (cnt > 0) ? (s / (float)cnt) * sc + of : 0.f;
}

extern "C" void kernel_launch(void* const* d_in, const int* in_sizes, int n_in,
                              void* d_out, int out_size, void* d_ws, size_t ws_size,
                              hipStream_t stream) {
    const float* x     = (const float*)d_in[0];
    const int*   ei    = (const int*)d_in[1];   // (2, E): row0=src, row1=dst
    const int*   batch = (const int*)d_in[2];
    const float* W1    = (const float*)d_in[3];
    const float* b1    = (const float*)d_in[4];
    const float* W2    = (const float*)d_in[5];
    const float* b2    = (const float*)d_in[6];
    const float* eps   = (const float*)d_in[7];
    const float* gamma = (const float*)d_in[8];
    const float* beta  = (const float*)d_in[9];
    float* out = (float*)d_out;

    char* ws = (char*)d_ws;
    size_t o = 0;
    auto alloc = [&](size_t bytes) -> char* {
        char* p = ws + o;
        o += (bytes + 255) & ~(size_t)255;
        return p;
    };
    int* off       = (int*)alloc((N_NODESC + 1) * sizeof(int));
    int* cursor    = (int*)alloc(N_NODESC * sizeof(int));
    int* csr       = (int*)alloc(N_EDGESC * sizeof(int));
    int* partials  = (int*)alloc(64 * sizeof(int));
    float* st      = (float*)alloc(3 * 2 * DF * sizeof(float));   // st[l] = st + l*256
    half8* wf      = (half8*)alloc((size_t)6 * 2048 * sizeof(half8));
    _Float16* hbuf = (_Float16*)alloc((size_t)N_NODESC * DF * sizeof(_Float16));
    _Float16* za   = (_Float16*)alloc((size_t)N_NODESC * DF * sizeof(_Float16));
    _Float16* zb   = (_Float16*)alloc((size_t)N_NODESC * DF * sizeof(_Float16));
    (void)ws_size; (void)in_sizes; (void)n_in; (void)out_size;

    const int* srcA = ei;
    const int* dstA = ei + N_EDGESC;

    const int NB_SCAN = (N_NODESC + 1023) / 1024;  // 49

    // CSR build
    hipMemsetAsync(off, 0, (N_NODESC + 1) * sizeof(int), stream);
    hipMemsetAsync(st, 0, 3 * 2 * DF * sizeof(float), stream);
    k_count<<<(N_EDGESC + 255) / 256, 256, 0, stream>>>(dstA, off);
    k_scan1<<<NB_SCAN, 1024, 0, stream>>>(off, partials);
    k_scan2<<<1, 64, 0, stream>>>(partials, NB_SCAN);
    k_scan3<<<NB_SCAN, 1024, 0, stream>>>(off, partials, cursor);
    k_scatter<<<(N_EDGESC + 255) / 256, 256, 0, stream>>>(srcA, dstA, cursor, csr);

    // weight repack + x conversion
    k_convW<<<(6 * 2048 + 255) / 256, 256, 0, stream>>>(W1, W2, wf);
    k_convX<<<(N_NODESC * DF / 4 + 255) / 256, 256, 0, stream>>>(x, hbuf);

    const int FUSED_GRID = (N_NODESC + 63) / 64;  // 782

    // layer 0: x -> z0 (za), stats -> st0
    k_fused<0><<<FUSED_GRID, 256, 0, stream>>>(
        hbuf, off, csr, eps, 0, nullptr, nullptr, nullptr,
        wf + 0 * 2048, b1 + 0 * DF, wf + 3 * 2048, b2 + 0 * DF, za, st + 0 * 256);
    // layer 1: z0 (+bn0+relu folded) -> z1 (zb), stats -> st1
    k_fused<1><<<FUSED_GRID, 256, 0, stream>>>(
        za, off, csr, eps, 1, st + 0 * 256, gamma + 0 * DF, beta + 0 * DF,
        wf + 1 * 2048, b1 + 1 * DF, wf + 4 * 2048, b2 + 1 * DF, zb, st + 1 * 256);
    // layer 2: z1 (+bn1+relu folded) -> z2 (za), stats -> st2
    k_fused<1><<<FUSED_GRID, 256, 0, stream>>>(
        zb, off, csr, eps, 2, st + 1 * 256, gamma + 1 * DF, beta + 1 * DF,
        wf + 2 * 2048, b1 + 2 * DF, wf + 5 * 2048, b2 + 2 * DF, za, st + 2 * 256);
    // pool with folded bn2 (no relu)
    k_pool<<<N_GRAPHSC, DF, 0, stream>>>(za, batch, st + 2 * 256, gamma + 2 * DF, beta + 2 * DF, out);
}